// Round 1
// 65.539 us; speedup vs baseline: 1.0001x; 1.0001x over previous
//
#include <hip/hip_runtime.h>

// out[i] = sum_b sum_t X[b, (i - t) mod D] * Y[b, t],  B=128, D=1024, fp32.
//
// v2: collapse the intermediate 32x vs previous version.
// Kernel 1 (cc_partial): grid 256 = (og=8 output slices of 128) x (bg=32
//   groups of 4 b), 512 thr, exactly 1 block/CU.
//   - 4 X rows staged 2x-replicated in LDS with rotate-swizzle (32 KB).
//   - Y read directly from global (L1-hot, 16 KB/block).
//   - thread (ig=tid>>5, ts=tid&31): 8 outputs x 32 t x 4 b = 1024 FMAs,
//     sliding 16-float register window, acc carried across the 4 b's.
//   - 32-way ts-reduce via wave shfl_xor butterfly (no LDS round trip);
//     lanes ts==0 store 2 float4 -> ws is only 128 KB (was 4 MB).
// Kernel 2 (cc_reduce): 4 blocks x 64 thr; out4[i4] = sum_bg ws4[bg*256+i4],
//   32 coalesced 1 KB-per-wave loads, one float4 store per thread.

#define CC_D 1024

__device__ __forceinline__ int swz(int f) {
  // rotate each 8-float4 row by the row index -> balanced banks for both
  // the ig-stride-2 and ts-stride-8 lane patterns
  return (f & ~7) | ((f + (f >> 3)) & 7);
}

__global__ __launch_bounds__(512) void cc_partial_kernel(
    const float* __restrict__ X, const float* __restrict__ Y,
    float* __restrict__ ws) {
  const int blk = blockIdx.x;   // 0..255
  const int og  = blk >> 5;     // 0..7   : outputs og*128 .. og*128+127
  const int bg  = blk & 31;     // 0..31  : batches 4*bg .. 4*bg+3
  const int tid = threadIdx.x;  // 0..511
  const int ig  = tid >> 5;     // 0..15  : outputs og*128 + 8*ig .. +7
  const int ts  = tid & 31;     // 0..31  : t = 32*ts .. 32*ts+31

  __shared__ __align__(16) float4 sm4[2048];  // 4 regions x 512 f4 (2x repl)

  // Stage 4 X rows, each replicated 2x, rotate-swizzled.
  {
    const int bb = tid >> 7;    // 0..3: which of the 4 rows
    const int u0 = tid & 127;
    const float4* Xr = (const float4*)X + (size_t)(4 * bg + bb) * 256;
    const float4 v0 = Xr[u0];
    const float4 v1 = Xr[u0 + 128];
    float4* R = sm4 + bb * 512;
    R[swz(u0)]       = v0;
    R[swz(u0 + 256)] = v0;   // replica
    R[swz(u0 + 128)] = v1;
    R[swz(u0 + 384)] = v1;   // replica
  }
  __syncthreads();

  // xlog[j] = X[b][j mod 1024], j in [0,2048). Window for (i=I0+q, t=t0+8g+r):
  // idx = 1024 + I0 + q - t0 - 8g - r = base_g + 8 + q - r,
  // base_g = 1024 + I0 - t0 - 8 - 8g, I0 = og*128 + 8*ig, t0 = 32*ts.
  // f0 = base_0/4 = 254 + og*32 + 2*ig - 8*ts  (range [6, 508], slides to >=0)
  const int f0 = 254 + og * 32 + 2 * ig - 8 * ts;

  float acc[8];
#pragma unroll
  for (int q = 0; q < 8; ++q) acc[q] = 0.f;

#pragma unroll
  for (int bi = 0; bi < 4; ++bi) {
    const float4* R = sm4 + bi * 512;
    const float* yrow = Y + (size_t)(4 * bg + bi) * CC_D + 32 * ts;

    float W[16];
#pragma unroll
    for (int m = 0; m < 4; ++m) {
      const float4 w = R[swz(f0 + m)];
      W[4 * m + 0] = w.x; W[4 * m + 1] = w.y;
      W[4 * m + 2] = w.z; W[4 * m + 3] = w.w;
    }

#pragma unroll
    for (int g = 0; g < 4; ++g) {
      const float4 ya = ((const float4*)(yrow + 8 * g))[0];
      const float4 yc = ((const float4*)(yrow + 8 * g))[1];
      const float y[8] = {ya.x, ya.y, ya.z, ya.w, yc.x, yc.y, yc.z, yc.w};

#pragma unroll
      for (int r = 0; r < 8; ++r)
#pragma unroll
        for (int q = 0; q < 8; ++q)
          acc[q] += W[8 + q - r] * y[r];

      if (g < 3) {
#pragma unroll
        for (int j = 0; j < 8; ++j) W[8 + j] = W[j];
        const float4 w0 = R[swz(f0 - 2 * (g + 1))];
        const float4 w1 = R[swz(f0 - 2 * (g + 1) + 1)];
        W[0] = w0.x; W[1] = w0.y; W[2] = w0.z; W[3] = w0.w;
        W[4] = w1.x; W[5] = w1.y; W[6] = w1.z; W[7] = w1.w;
      }
    }
  }

  // Reduce over the 32 ts lanes (lane bits 0..4) with a butterfly; every
  // 32-lane group shares one ig, so lanes ts==0 end with the full t-sum.
#pragma unroll
  for (int o = 1; o < 32; o <<= 1)
#pragma unroll
    for (int q = 0; q < 8; ++q) acc[q] += __shfl_xor(acc[q], o, 64);

  if (ts == 0) {
    const int i4 = og * 32 + 2 * ig;          // output float4 index
    float4* w4 = (float4*)ws;                 // layout ws4[bg][i4] (32 x 256)
    w4[(size_t)bg * 256 + i4]     = make_float4(acc[0], acc[1], acc[2], acc[3]);
    w4[(size_t)bg * 256 + i4 + 1] = make_float4(acc[4], acc[5], acc[6], acc[7]);
  }
}

__global__ __launch_bounds__(64) void cc_reduce_kernel(
    const float* __restrict__ ws, float* __restrict__ out) {
  const int i4 = blockIdx.x * 64 + threadIdx.x;  // 0..255
  const float4* w4 = (const float4*)ws;
  float4 s = make_float4(0.f, 0.f, 0.f, 0.f);
#pragma unroll
  for (int bg = 0; bg < 32; ++bg) {
    const float4 v = w4[(size_t)bg * 256 + i4];  // lane-contiguous, coalesced
    s.x += v.x; s.y += v.y; s.z += v.z; s.w += v.w;
  }
  ((float4*)out)[i4] = s;
}

extern "C" void kernel_launch(void* const* d_in, const int* in_sizes, int n_in,
                              void* d_out, int out_size, void* d_ws,
                              size_t ws_size, hipStream_t stream) {
  const float* X = (const float*)d_in[0];  // (128, 1024) f32
  const float* Y = (const float*)d_in[1];  // (128, 1024) f32
  float* out = (float*)d_out;              // 1024 f32
  float* ws  = (float*)d_ws;               // 128 KB used

  cc_partial_kernel<<<256, 512, 0, stream>>>(X, Y, ws);
  cc_reduce_kernel<<<4, 64, 0, stream>>>(ws, out);
}